// Round 29
// baseline (280.742 us; speedup 1.0000x reference)
//
#include <hip/hip_runtime.h>
#include <hip/hip_bf16.h>
#include <cstdint>

typedef __bf16 bf16x8 __attribute__((ext_vector_type(8)));
typedef float  f32x4  __attribute__((ext_vector_type(4)));

struct alignas(4) us2 { unsigned short x, y; };
struct alignas(8) us4 { unsigned short x, y, z, w; };

__device__ __forceinline__ unsigned short f2bf(float f) {
    union { float f; unsigned u; } a; a.f = f;
    unsigned r = a.u + 0x7fffu + ((a.u >> 16) & 1u);   // round-to-nearest-even
    return (unsigned short)(r >> 16);
}

__device__ __forceinline__ void gl_lds16(const void* g, void* s) {
    __builtin_amdgcn_global_load_lds(
        (const __attribute__((address_space(1))) void*)g,
        (__attribute__((address_space(3))) void*)s, 16, 0, 0);
}

#define SCHEDB()  __builtin_amdgcn_sched_barrier(0)
#define SBAR()    do { SCHEDB(); __builtin_amdgcn_s_barrier(); SCHEDB(); } while (0)
#define WAITLG(N) do { asm volatile("s_waitcnt lgkmcnt(" #N ")" ::: "memory"); SCHEDB(); } while (0)
#define WAITVM(N) do { asm volatile("s_waitcnt vmcnt(" #N ")" ::: "memory"); SCHEDB(); } while (0)

// C = A(MxK) @ W(NxK)^T, bf16 in, fp32 acc. 256x256 tile.
// R29 = R28 (271.7us, MfmaUtil 50.5%, Occ 42%) MINUS s_setprio. T5's mechanism
// needs wave role-split (m218b); on uniform-wave GEMM structures setprio
// measured NEGATIVE (m190: -14TF). Here 16 symmetric waves at 4/SIMD overlap
// by waves issuing ds_reads WHILE others MFMA - setprio(1) around the cluster
// deprioritizes co-resident waves' LDS issue on the same SIMD, delaying their
// next cluster. Hint-only instruction -> zero correctness risk.
// Schedule per half h (R27 pre-barrier-read pipeline, race-free):
//   WAITVM(2) [own stage(h+1); ladder 2/0] -> SBAR [slots h,h+1 block-wide]
//   -> WAITLG(0) [own pre-issued reads of slot h] -> 16 MFMA (A-reads of slot
//   h+1 interleaved at mf-group boundaries) -> stage(h+3) -> B reads of h+1.
// 1024 threads / 16 waves (4Mx4N), wave-tile 64x64, acc[4][4] (64 AGPR),
// 4 waves/SIMD. Ring of 4 K-32 half-slots (A 16KB + B 16KB, 128KB).
// Swizzle: R3-proven row-bits[2:1] XOR (0 conflicts measured).
// EPI 0: outb = bf16(gelu_exact(acc+bias)) ; EPI 1: outf = acc+bias ;
// EPI 2: fused coupling, W3 interleaved by 16-col blocks (s-block | t-block).
template<int EPI, int K, int N>
__global__ __launch_bounds__(1024)
void gemm256(const unsigned short* __restrict__ A,
             const unsigned short* __restrict__ W,
             const float* __restrict__ bias,
             unsigned short* __restrict__ outb,
             float* __restrict__ outf,
             const float* __restrict__ zin,
             float* __restrict__ ldout)
{
    extern __shared__ char smem[];
    constexpr int NH = K / 32;           // number of K-32 halves (16 or 64)
    constexpr int GX = N / 256;

    const int tid  = threadIdx.x;
    const int lane = tid & 63;
    const int wv   = tid >> 6;           // 0..15
    const int wr   = wv >> 2, wc = wv & 3;

    // T1: bijective XCD swizzle (nwg divisible by 8 for all our shapes)
    const int bid = blockIdx.y * GX + blockIdx.x;
    const int nwg = GX * (int)gridDim.y;
    const int swz = (bid & 7) * (nwg >> 3) + (bid >> 3);
    const size_t row0 = (size_t)(swz / GX) * 256;
    const size_t col0 = (size_t)(swz % GX) * 256;

    // LDS: A ring = 4 x 16KB at +0 ; B ring = 4 x 16KB at +65536.
    // Half-slot: 256 rows x 64B. Chunk c (16B): row c>>2, pos c&3, holds
    // src k-chunk (c&3) ^ ((row>>1)&3)   [R3 swizzle, 0-conflict]
    const int cse = (((tid & 3) ^ ((tid >> 3) & 3)) << 3);  // src elem offset
    const unsigned short* ag = A + (row0 + (tid >> 2)) * (size_t)K + cse;
    const unsigned short* bg = W + (col0 + (tid >> 2)) * (size_t)K + cse;

    auto stage = [&](int hh) {           // 2 x gl_lds (full A + B half-slots)
        char* dA = smem + (hh & 3) * 16384 + tid * 16;
        char* dB = dA + 65536;
        gl_lds16(ag + (size_t)hh * 32, dA);
        gl_lds16(bg + (size_t)hh * 32, dB);
    };

    // fragment reads: byte = row*64 + ((lane>>4) ^ ((row>>1)&3))*16
    const int ln15 = lane & 15;
    const int xo   = (((lane >> 4) ^ ((ln15 >> 1) & 3)) << 4);
    const int arow = wr * 64 + ln15;                        // + mi*16 (mi 0..3)
    const int brow = wc * 64 + ln15;                        // + nf*16 (nf 0..3)

#define LD(base, row) (*(const bf16x8*)((base) + (size_t)(row) * 64 + xo))

    f32x4 acc[4][4] = {};
    bf16x8 aF[4], bF[4];

    // prologue: stage 0,1,2 -> own cert of stage(0) -> BARRIER (block-wide)
    // -> issue slot-0 reads (certified data; reads float across next barrier)
    stage(0); stage(1); stage(2);
    WAITVM(4);                           // own stage(0) landed (1,2 in flight)
    SBAR();                              // block-wide: slot 0 landed
#pragma unroll
    for (int mf = 0; mf < 4; ++mf) aF[mf] = LD(smem, arow + mf * 16);
#pragma unroll
    for (int nf = 0; nf < 4; ++nf) bF[nf] = LD(smem + 65536, brow + nf * 16);

    for (int h = 0; h < NH; ++h) {
        // pre-barrier: certify OWN stage(h+1); barrier makes it block-wide.
        if (h <= NH - 3) WAITVM(2);
        else             WAITVM(0);
        SBAR();                          // slots h, h+1 block-wide landed

        WAITLG(0);                       // own pre-issued reads of slot h
        const bool more = (h + 1 < NH);
        const char* cAn = smem + ((h + 1) & 3) * 16384;
        const char* cBn = cAn + 65536;

#pragma unroll
        for (int mf = 0; mf < 4; ++mf) {
#pragma unroll
            for (int nf = 0; nf < 4; ++nf)
                acc[mf][nf] = __builtin_amdgcn_mfma_f32_16x16x32_bf16(
                    aF[mf], bF[nf], acc[mf][nf], 0, 0, 0);
            if (more) aF[mf] = LD(cAn, arow + mf * 16);   // reg dead; interleave
        }

        if (h + 3 < NH) stage(h + 3);
        if (more) {                      // B reads post-cluster (bF live above)
#pragma unroll
            for (int nf = 0; nf < 4; ++nf) bF[nf] = LD(cBn, brow + nf * 16);
            SCHEDB();
        }
    }
#undef LD

    // epilogue: D layout col = lane&15, row = (lane>>4)*4 + reg
    const int lq = lane >> 4;
    float bv[4];
#pragma unroll
    for (int nf = 0; nf < 4; ++nf) bv[nf] = bias[col0 + wc * 64 + nf * 16 + ln15];

    if (EPI == 2) {
        // W interleaved by 16-col blocks: nf=2p -> s, nf=2p+1 -> t, same j.
        const float2* zin2 = (const float2*)zin;
        float2*       out2 = (float2*)outf;
#pragma unroll
        for (int mi = 0; mi < 4; ++mi) {
#pragma unroll
            for (int r = 0; r < 4; ++r) {
                const size_t row = row0 + wr * 64 + mi * 16 + lq * 4 + r;
                float sv = 0.f;
#pragma unroll
                for (int p = 0; p < 2; ++p) {
                    float s = acc[mi][2 * p][r] + bv[2 * p];
                    float t = acc[mi][2 * p + 1][r] + bv[2 * p + 1];
                    const size_t j = (col0 >> 1) + wc * 32 + p * 16 + ln15;
                    float2 zv = zin2[row * 512 + j];
                    float2 o; o.x = zv.x; o.y = zv.y * __expf(s) + t;
                    out2[row * 512 + j] = o;
                    sv += s;
                }
                sv += __shfl_xor(sv, 1, 64);
                sv += __shfl_xor(sv, 2, 64);
                sv += __shfl_xor(sv, 4, 64);
                sv += __shfl_xor(sv, 8, 64);
                if (ln15 == 0) atomicAdd(&ldout[row], sv);
            }
        }
    } else {
#pragma unroll
        for (int mi = 0; mi < 4; ++mi) {
#pragma unroll
            for (int r = 0; r < 4; ++r) {
                const size_t row = row0 + wr * 64 + mi * 16 + lq * 4 + r;
#pragma unroll
                for (int nf = 0; nf < 4; ++nf) {
                    const size_t col = col0 + wc * 64 + nf * 16 + ln15;
                    float v = acc[mi][nf][r] + bv[nf];
                    if (EPI == 0) {
                        float g = 0.5f * v * (1.0f + erff(v * 0.70710678118654752f));
                        outb[row * N + col] = f2bf(g);
                    } else {
                        outf[row * N + col] = v;
                    }
                }
            }
        }
    }
}

// One fused prep pass: W1/W2 cvt, W3 interleave-by-16 cvt, pack_even, b3i, ldout.
__global__ void prep_all(const float* __restrict__ W1, const float* __restrict__ W2,
                         const float* __restrict__ W3, const float* __restrict__ b3,
                         const float* __restrict__ z,  const float* __restrict__ ld,
                         unsigned short* __restrict__ w1b, unsigned short* __restrict__ w2b,
                         unsigned short* __restrict__ w3i, float* __restrict__ b3i,
                         unsigned short* __restrict__ zm,  float* __restrict__ ldout)
{
    constexpr int N1 = 2048 * 512 / 4;
    constexpr int N2 = 2048 * 2048 / 4;
    constexpr int N3 = 1024 * 2048 / 4;
    constexpr int N4 = 16384 * 1024 / 4;
    constexpr int N5 = 1024;
    constexpr int N6 = 16384;
    constexpr int TOT = N1 + N2 + N3 + N4 + N5 + N6;
    const int stride = gridDim.x * blockDim.x;
    for (int i = blockIdx.x * blockDim.x + threadIdx.x; i < TOT; i += stride) {
        int j = i;
        if (j < N1) {
            float4 v = ((const float4*)W1)[j];
            ((us4*)w1b)[j] = us4{ f2bf(v.x), f2bf(v.y), f2bf(v.z), f2bf(v.w) };
            continue;
        }
        j -= N1;
        if (j < N2) {
            float4 v = ((const float4*)W2)[j];
            ((us4*)w2b)[j] = us4{ f2bf(v.x), f2bf(v.y), f2bf(v.z), f2bf(v.w) };
            continue;
        }
        j -= N2;
        if (j < N3) {
            int row = j >> 9, c4 = j & 511;
            int q = row >> 5, u = row & 31;
            int srcrow = (u < 16) ? (q * 16 + u) : (512 + q * 16 + u - 16);
            float4 v = ((const float4*)W3)[(size_t)srcrow * 512 + c4];
            ((us4*)w3i)[j] = us4{ f2bf(v.x), f2bf(v.y), f2bf(v.z), f2bf(v.w) };
            continue;
        }
        j -= N3;
        if (j < N4) {
            float4 v = ((const float4*)z)[j];
            ((us2*)zm)[j] = us2{ f2bf(v.x), f2bf(v.z) };
            continue;
        }
        j -= N4;
        if (j < N5) {
            int q = j >> 5, u = j & 31;
            b3i[j] = b3[(u < 16) ? (q * 16 + u) : (512 + q * 16 + u - 16)];
            continue;
        }
        j -= N5;
        ldout[j] = ld[j];
    }
}

extern "C" void kernel_launch(void* const* d_in, const int* in_sizes, int n_in,
                              void* d_out, int out_size, void* d_ws, size_t ws_size,
                              hipStream_t stream)
{
    const float* z  = (const float*)d_in[0];
    const float* ld = (const float*)d_in[1];
    const float* W1 = (const float*)d_in[2];
    const float* b1 = (const float*)d_in[3];
    const float* W2 = (const float*)d_in[4];
    const float* b2 = (const float*)d_in[5];
    const float* W3 = (const float*)d_in[6];
    const float* b3 = (const float*)d_in[7];

    float* out   = (float*)d_out;
    float* zout  = out;
    float* ldout = out + (size_t)16384 * 1024;

    char* w = (char*)d_ws;
    unsigned short* zm  = (unsigned short*)w; w += (size_t)16384 * 512 * 2;
    unsigned short* w1b = (unsigned short*)w; w += (size_t)2048 * 512 * 2;
    unsigned short* w2b = (unsigned short*)w; w += (size_t)2048 * 2048 * 2;
    unsigned short* w3i = (unsigned short*)w; w += (size_t)1024 * 2048 * 2;
    unsigned short* h1  = (unsigned short*)w; w += (size_t)16384 * 2048 * 2;
    unsigned short* h2  = (unsigned short*)w; w += (size_t)16384 * 2048 * 2;
    float*          b3i = (float*)w;          w += 1024 * 4;

    (void)hipFuncSetAttribute((const void*)&gemm256<0, 512,  2048>,
                              hipFuncAttributeMaxDynamicSharedMemorySize, 131072);
    (void)hipFuncSetAttribute((const void*)&gemm256<0, 2048, 2048>,
                              hipFuncAttributeMaxDynamicSharedMemorySize, 131072);
    (void)hipFuncSetAttribute((const void*)&gemm256<2, 2048, 1024>,
                              hipFuncAttributeMaxDynamicSharedMemorySize, 131072);

    prep_all<<<2048, 256, 0, stream>>>(W1, W2, W3, b3, z, ld,
                                       w1b, w2b, w3i, b3i, zm, ldout);

    gemm256<0, 512,  2048><<<dim3(8, 64), 1024, 131072, stream>>>(zm, w1b, b1, h1, nullptr, nullptr, nullptr);
    gemm256<0, 2048, 2048><<<dim3(8, 64), 1024, 131072, stream>>>(h1, w2b, b2, h2, nullptr, nullptr, nullptr);
    gemm256<2, 2048, 1024><<<dim3(4, 64), 1024, 131072, stream>>>(h2, w3i, b3i, nullptr, zout, z, ldout);
}

// Round 30
// 271.609 us; speedup vs baseline: 1.0336x; 1.0336x over previous
//
#include <hip/hip_runtime.h>
#include <hip/hip_bf16.h>
#include <cstdint>

typedef __bf16 bf16x8 __attribute__((ext_vector_type(8)));
typedef float  f32x4  __attribute__((ext_vector_type(4)));

struct alignas(4) us2 { unsigned short x, y; };
struct alignas(8) us4 { unsigned short x, y, z, w; };

__device__ __forceinline__ unsigned short f2bf(float f) {
    union { float f; unsigned u; } a; a.f = f;
    unsigned r = a.u + 0x7fffu + ((a.u >> 16) & 1u);   // round-to-nearest-even
    return (unsigned short)(r >> 16);
}

__device__ __forceinline__ void gl_lds16(const void* g, void* s) {
    __builtin_amdgcn_global_load_lds(
        (const __attribute__((address_space(1))) void*)g,
        (__attribute__((address_space(3))) void*)s, 16, 0, 0);
}

#define SCHEDB()  __builtin_amdgcn_sched_barrier(0)
#define SBAR()    do { SCHEDB(); __builtin_amdgcn_s_barrier(); SCHEDB(); } while (0)
#define WAITLG(N) do { asm volatile("s_waitcnt lgkmcnt(" #N ")" ::: "memory"); SCHEDB(); } while (0)
#define WAITVM(N) do { asm volatile("s_waitcnt vmcnt(" #N ")" ::: "memory"); SCHEDB(); } while (0)

// C = A(MxK) @ W(NxK)^T, bf16 in, fp32 acc. 256x256 tile.
// FINAL (session-best R28: 271.66us measured; R27 twin at 271.77us).
// 29-round ladder: 435.8 -> 271.7us. Key structure:
//  - 1024 threads / 16 waves (4Mx4N), wave-tile 64x64, acc[4][4] (64 AGPR),
//    4 waves/SIMD: TLP covers LDS latency + barrier convergence (R24, +15%).
//  - Ring of 4 K-32 half-slots (A 16KB + B 16KB, 128KB LDS). Stage h+3
//    during h via global_load_lds (2/thread/half). Counted WAITVM ladder.
//  - Pre-barrier reads (R27): per half h: {own WAITVM(2) -> SBAR} block-
//    certifies slots h AND h+1 -> WAITLG(0) (own pre-issued slot-h reads,
//    latency absorbed by barrier) -> 16-MFMA cluster with slot-(h+1) A-reads
//    interleaved at mf-group boundaries (regs dead; R28) -> stage(h+3) ->
//    B reads of h+1. Race-free: reads of h+1 only after its block-wide cert;
//    reuse safe: stage(h+5) is >=2 barriers later.
//  - Swizzle: R3-proven row-bits[2:1] XOR (0 bank conflicts measured).
//  - Fused epilogues: GELU into GEMM1/2 (bf16 store), coupling+log_det into
//    GEMM3 (W3 interleaved by 16-col s|t blocks; float2-coalesced; WRITE at
//    the 65.5MB ideal).
// Refuted (do not revisit): 32x32x16 MFMA (b128 conflicts), occupancy via
// tile resize (spill / no TLP), split epilogue (+14us), x4 unroll (spill),
// m201 single-lever ports, setprio removal (total noise-regressed).
template<int EPI, int K, int N>
__global__ __launch_bounds__(1024)
void gemm256(const unsigned short* __restrict__ A,
             const unsigned short* __restrict__ W,
             const float* __restrict__ bias,
             unsigned short* __restrict__ outb,
             float* __restrict__ outf,
             const float* __restrict__ zin,
             float* __restrict__ ldout)
{
    extern __shared__ char smem[];
    constexpr int NH = K / 32;           // number of K-32 halves (16 or 64)
    constexpr int GX = N / 256;

    const int tid  = threadIdx.x;
    const int lane = tid & 63;
    const int wv   = tid >> 6;           // 0..15
    const int wr   = wv >> 2, wc = wv & 3;

    // T1: bijective XCD swizzle (nwg divisible by 8 for all our shapes)
    const int bid = blockIdx.y * GX + blockIdx.x;
    const int nwg = GX * (int)gridDim.y;
    const int swz = (bid & 7) * (nwg >> 3) + (bid >> 3);
    const size_t row0 = (size_t)(swz / GX) * 256;
    const size_t col0 = (size_t)(swz % GX) * 256;

    // LDS: A ring = 4 x 16KB at +0 ; B ring = 4 x 16KB at +65536.
    // Half-slot: 256 rows x 64B. Chunk c (16B): row c>>2, pos c&3, holds
    // src k-chunk (c&3) ^ ((row>>1)&3)   [R3 swizzle, 0-conflict]
    const int cse = (((tid & 3) ^ ((tid >> 3) & 3)) << 3);  // src elem offset
    const unsigned short* ag = A + (row0 + (tid >> 2)) * (size_t)K + cse;
    const unsigned short* bg = W + (col0 + (tid >> 2)) * (size_t)K + cse;

    auto stage = [&](int hh) {           // 2 x gl_lds (full A + B half-slots)
        char* dA = smem + (hh & 3) * 16384 + tid * 16;
        char* dB = dA + 65536;
        gl_lds16(ag + (size_t)hh * 32, dA);
        gl_lds16(bg + (size_t)hh * 32, dB);
    };

    // fragment reads: byte = row*64 + ((lane>>4) ^ ((row>>1)&3))*16
    const int ln15 = lane & 15;
    const int xo   = (((lane >> 4) ^ ((ln15 >> 1) & 3)) << 4);
    const int arow = wr * 64 + ln15;                        // + mi*16 (mi 0..3)
    const int brow = wc * 64 + ln15;                        // + nf*16 (nf 0..3)

#define LD(base, row) (*(const bf16x8*)((base) + (size_t)(row) * 64 + xo))

    f32x4 acc[4][4] = {};
    bf16x8 aF[4], bF[4];

    // prologue: stage 0,1,2 -> own cert of stage(0) -> BARRIER (block-wide)
    // -> issue slot-0 reads (certified data; reads float across next barrier)
    stage(0); stage(1); stage(2);
    WAITVM(4);                           // own stage(0) landed (1,2 in flight)
    SBAR();                              // block-wide: slot 0 landed
#pragma unroll
    for (int mf = 0; mf < 4; ++mf) aF[mf] = LD(smem, arow + mf * 16);
#pragma unroll
    for (int nf = 0; nf < 4; ++nf) bF[nf] = LD(smem + 65536, brow + nf * 16);

    for (int h = 0; h < NH; ++h) {
        // pre-barrier: certify OWN stage(h+1); barrier makes it block-wide.
        if (h <= NH - 3) WAITVM(2);
        else             WAITVM(0);
        SBAR();                          // slots h, h+1 block-wide landed

        WAITLG(0);                       // own pre-issued reads of slot h
        const bool more = (h + 1 < NH);
        const char* cAn = smem + ((h + 1) & 3) * 16384;
        const char* cBn = cAn + 65536;

        __builtin_amdgcn_s_setprio(1);
#pragma unroll
        for (int mf = 0; mf < 4; ++mf) {
#pragma unroll
            for (int nf = 0; nf < 4; ++nf)
                acc[mf][nf] = __builtin_amdgcn_mfma_f32_16x16x32_bf16(
                    aF[mf], bF[nf], acc[mf][nf], 0, 0, 0);
            if (more) aF[mf] = LD(cAn, arow + mf * 16);   // reg dead; interleave
        }
        __builtin_amdgcn_s_setprio(0);

        if (h + 3 < NH) stage(h + 3);
        if (more) {                      // B reads post-cluster (bF live above)
#pragma unroll
            for (int nf = 0; nf < 4; ++nf) bF[nf] = LD(cBn, brow + nf * 16);
            SCHEDB();
        }
    }
#undef LD

    // epilogue: D layout col = lane&15, row = (lane>>4)*4 + reg
    const int lq = lane >> 4;
    float bv[4];
#pragma unroll
    for (int nf = 0; nf < 4; ++nf) bv[nf] = bias[col0 + wc * 64 + nf * 16 + ln15];

    if (EPI == 2) {
        // W interleaved by 16-col blocks: nf=2p -> s, nf=2p+1 -> t, same j.
        const float2* zin2 = (const float2*)zin;
        float2*       out2 = (float2*)outf;
#pragma unroll
        for (int mi = 0; mi < 4; ++mi) {
#pragma unroll
            for (int r = 0; r < 4; ++r) {
                const size_t row = row0 + wr * 64 + mi * 16 + lq * 4 + r;
                float sv = 0.f;
#pragma unroll
                for (int p = 0; p < 2; ++p) {
                    float s = acc[mi][2 * p][r] + bv[2 * p];
                    float t = acc[mi][2 * p + 1][r] + bv[2 * p + 1];
                    const size_t j = (col0 >> 1) + wc * 32 + p * 16 + ln15;
                    float2 zv = zin2[row * 512 + j];
                    float2 o; o.x = zv.x; o.y = zv.y * __expf(s) + t;
                    out2[row * 512 + j] = o;
                    sv += s;
                }
                sv += __shfl_xor(sv, 1, 64);
                sv += __shfl_xor(sv, 2, 64);
                sv += __shfl_xor(sv, 4, 64);
                sv += __shfl_xor(sv, 8, 64);
                if (ln15 == 0) atomicAdd(&ldout[row], sv);
            }
        }
    } else {
#pragma unroll
        for (int mi = 0; mi < 4; ++mi) {
#pragma unroll
            for (int r = 0; r < 4; ++r) {
                const size_t row = row0 + wr * 64 + mi * 16 + lq * 4 + r;
#pragma unroll
                for (int nf = 0; nf < 4; ++nf) {
                    const size_t col = col0 + wc * 64 + nf * 16 + ln15;
                    float v = acc[mi][nf][r] + bv[nf];
                    if (EPI == 0) {
                        float g = 0.5f * v * (1.0f + erff(v * 0.70710678118654752f));
                        outb[row * N + col] = f2bf(g);
                    } else {
                        outf[row * N + col] = v;
                    }
                }
            }
        }
    }
}

// One fused prep pass: W1/W2 cvt, W3 interleave-by-16 cvt, pack_even, b3i, ldout.
__global__ void prep_all(const float* __restrict__ W1, const float* __restrict__ W2,
                         const float* __restrict__ W3, const float* __restrict__ b3,
                         const float* __restrict__ z,  const float* __restrict__ ld,
                         unsigned short* __restrict__ w1b, unsigned short* __restrict__ w2b,
                         unsigned short* __restrict__ w3i, float* __restrict__ b3i,
                         unsigned short* __restrict__ zm,  float* __restrict__ ldout)
{
    constexpr int N1 = 2048 * 512 / 4;
    constexpr int N2 = 2048 * 2048 / 4;
    constexpr int N3 = 1024 * 2048 / 4;
    constexpr int N4 = 16384 * 1024 / 4;
    constexpr int N5 = 1024;
    constexpr int N6 = 16384;
    constexpr int TOT = N1 + N2 + N3 + N4 + N5 + N6;
    const int stride = gridDim.x * blockDim.x;
    for (int i = blockIdx.x * blockDim.x + threadIdx.x; i < TOT; i += stride) {
        int j = i;
        if (j < N1) {
            float4 v = ((const float4*)W1)[j];
            ((us4*)w1b)[j] = us4{ f2bf(v.x), f2bf(v.y), f2bf(v.z), f2bf(v.w) };
            continue;
        }
        j -= N1;
        if (j < N2) {
            float4 v = ((const float4*)W2)[j];
            ((us4*)w2b)[j] = us4{ f2bf(v.x), f2bf(v.y), f2bf(v.z), f2bf(v.w) };
            continue;
        }
        j -= N2;
        if (j < N3) {
            int row = j >> 9, c4 = j & 511;
            int q = row >> 5, u = row & 31;
            int srcrow = (u < 16) ? (q * 16 + u) : (512 + q * 16 + u - 16);
            float4 v = ((const float4*)W3)[(size_t)srcrow * 512 + c4];
            ((us4*)w3i)[j] = us4{ f2bf(v.x), f2bf(v.y), f2bf(v.z), f2bf(v.w) };
            continue;
        }
        j -= N3;
        if (j < N4) {
            float4 v = ((const float4*)z)[j];
            ((us2*)zm)[j] = us2{ f2bf(v.x), f2bf(v.z) };
            continue;
        }
        j -= N4;
        if (j < N5) {
            int q = j >> 5, u = j & 31;
            b3i[j] = b3[(u < 16) ? (q * 16 + u) : (512 + q * 16 + u - 16)];
            continue;
        }
        j -= N5;
        ldout[j] = ld[j];
    }
}

extern "C" void kernel_launch(void* const* d_in, const int* in_sizes, int n_in,
                              void* d_out, int out_size, void* d_ws, size_t ws_size,
                              hipStream_t stream)
{
    const float* z  = (const float*)d_in[0];
    const float* ld = (const float*)d_in[1];
    const float* W1 = (const float*)d_in[2];
    const float* b1 = (const float*)d_in[3];
    const float* W2 = (const float*)d_in[4];
    const float* b2 = (const float*)d_in[5];
    const float* W3 = (const float*)d_in[6];
    const float* b3 = (const float*)d_in[7];

    float* out   = (float*)d_out;
    float* zout  = out;
    float* ldout = out + (size_t)16384 * 1024;

    char* w = (char*)d_ws;
    unsigned short* zm  = (unsigned short*)w; w += (size_t)16384 * 512 * 2;
    unsigned short* w1b = (unsigned short*)w; w += (size_t)2048 * 512 * 2;
    unsigned short* w2b = (unsigned short*)w; w += (size_t)2048 * 2048 * 2;
    unsigned short* w3i = (unsigned short*)w; w += (size_t)1024 * 2048 * 2;
    unsigned short* h1  = (unsigned short*)w; w += (size_t)16384 * 2048 * 2;
    unsigned short* h2  = (unsigned short*)w; w += (size_t)16384 * 2048 * 2;
    float*          b3i = (float*)w;          w += 1024 * 4;

    (void)hipFuncSetAttribute((const void*)&gemm256<0, 512,  2048>,
                              hipFuncAttributeMaxDynamicSharedMemorySize, 131072);
    (void)hipFuncSetAttribute((const void*)&gemm256<0, 2048, 2048>,
                              hipFuncAttributeMaxDynamicSharedMemorySize, 131072);
    (void)hipFuncSetAttribute((const void*)&gemm256<2, 2048, 1024>,
                              hipFuncAttributeMaxDynamicSharedMemorySize, 131072);

    prep_all<<<2048, 256, 0, stream>>>(W1, W2, W3, b3, z, ld,
                                       w1b, w2b, w3i, b3i, zm, ldout);

    gemm256<0, 512,  2048><<<dim3(8, 64), 1024, 131072, stream>>>(zm, w1b, b1, h1, nullptr, nullptr, nullptr);
    gemm256<0, 2048, 2048><<<dim3(8, 64), 1024, 131072, stream>>>(h1, w2b, b2, h2, nullptr, nullptr, nullptr);
    gemm256<2, 2048, 1024><<<dim3(4, 64), 1024, 131072, stream>>>(h2, w3i, b3i, nullptr, zout, z, ldout);
}